// Round 9
// baseline (245.425 us; speedup 1.0000x reference)
//
#include <hip/hip_runtime.h>

// ---------------------------------------------------------------------------
// RelativeAttention: out = softmax(QK^T*scale + relbias + mask) V, + proj
// B=4 H=8 N=2048 C=512 hd=64.  bf16 MFMA pipeline, f32 accum.
// R9: bias moved out of LDS — loaded f32 from Btab (L1-resident) during the
//     mask prefetch and FOLDED into it: mn=(mask+bias)*log2e. Removes 32
//     scalar LDS reads + 32 unpack VALU per lane per kv-tile (the #2 LDS
//     line item). Rest identical to R8.
// ---------------------------------------------------------------------------

typedef __attribute__((ext_vector_type(8))) short short8;   // 8 bf16 (4 VGPR)
typedef __attribute__((ext_vector_type(4))) float f32x4;    // MFMA C/D

#define SEQ   2048
#define NHEAD 8
#define NBATCH 4
#define HD    64
#define CDIM  512
#define L2E   1.44269504f

__device__ __forceinline__ unsigned short f32_to_bf16_rn(float f) {
  unsigned u = __builtin_bit_cast(unsigned, f);
  u += 0x7FFFu + ((u >> 16) & 1u);
  return (unsigned short)(u >> 16);
}

// -------------------------------- f32 -> bf16 convert (vectorized) ----------
__global__ __launch_bounds__(256) void cvt_f32_bf16(const float* __restrict__ in,
                                                    ushort* __restrict__ out, int n4) {
  int i = blockIdx.x * 256 + threadIdx.x;
  const int stride = gridDim.x * 256;
  for (; i < n4; i += stride) {
    float4 v = reinterpret_cast<const float4*>(in)[i];
    ushort4 o;
    o.x = f32_to_bf16_rn(v.x);
    o.y = f32_to_bf16_rn(v.y);
    o.z = f32_to_bf16_rn(v.z);
    o.w = f32_to_bf16_rn(v.w);
    reinterpret_cast<ushort4*>(out)[i] = o;
  }
}

// -------------------------------- NT GEMM: C = A(MxK) * B(NxK)^T ------------
// 128x128 tile, 4 waves (2x2), each wave 64x64 = 4x4 frags of 16x16x32 bf16.
// MODE 0: QKV epilogue -> scatter q[b,h,n,d], k[b,h,n,d], vT[b,h,d,n] (bf16)
// MODE 1: proj epilogue -> f32 out += bias
template <int MODE>
__global__ __launch_bounds__(256) void gemm_nt(
    const ushort* __restrict__ A, const ushort* __restrict__ Bm,
    ushort* __restrict__ qo, ushort* __restrict__ ko, ushort* __restrict__ vto,
    const float* __restrict__ bias, float* __restrict__ outf) {
  const int K = 512;
  __shared__ ushort As[128 * 40];
  __shared__ ushort Bs[128 * 40];

  const int t = threadIdx.x;
  const int bn = blockIdx.x, bm = blockIdx.y;
  const int lane = t & 63, w = t >> 6;
  const int wm = w >> 1, wn = w & 1;
  const int lr = lane & 15, lq = lane >> 4;
  const int m0 = bm * 128, n0 = bn * 128;

  f32x4 acc[4][4];
#pragma unroll
  for (int i = 0; i < 4; ++i)
#pragma unroll
    for (int j = 0; j < 4; ++j) acc[i][j] = (f32x4){0.f, 0.f, 0.f, 0.f};

  for (int kt = 0; kt < K; kt += 32) {
#pragma unroll
    for (int p = 0; p < 2; ++p) {
      const int flat = p * 256 + t;
      const int row = flat >> 2, seg = flat & 3;
      *(uint4*)&As[row * 40 + seg * 8] =
          *(const uint4*)(A + (size_t)(m0 + row) * K + kt + seg * 8);
      *(uint4*)&Bs[row * 40 + seg * 8] =
          *(const uint4*)(Bm + (size_t)(n0 + row) * K + kt + seg * 8);
    }
    __syncthreads();

    short8 af[4], bf[4];
#pragma unroll
    for (int i = 0; i < 4; ++i) {
      af[i] = *(const short8*)&As[(wm * 64 + i * 16 + lr) * 40 + lq * 8];
      bf[i] = *(const short8*)&Bs[(wn * 64 + i * 16 + lr) * 40 + lq * 8];
    }
#pragma unroll
    for (int i = 0; i < 4; ++i)
#pragma unroll
      for (int j = 0; j < 4; ++j)
        acc[i][j] = __builtin_amdgcn_mfma_f32_16x16x32_bf16(af[i], bf[j], acc[i][j], 0, 0, 0);
    __syncthreads();
  }

  if constexpr (MODE == 0) {
#pragma unroll
    for (int i = 0; i < 4; ++i) {
      const int mbase = m0 + wm * 64 + i * 16 + lq * 4;  // + r
      const int bb = mbase >> 11;
      const int s0 = mbase & 2047;
#pragma unroll
      for (int j = 0; j < 4; ++j) {
        const int nb = n0 + wn * 64 + j * 16;
        const int tt = nb >> 9;
        const int hh = (nb >> 6) & 7;
        const int d0 = nb & 63;
        const int bh = bb * NHEAD + hh;
        if (tt == 2) {
          ushort4 pk;
          pk.x = f32_to_bf16_rn(acc[i][j][0]);
          pk.y = f32_to_bf16_rn(acc[i][j][1]);
          pk.z = f32_to_bf16_rn(acc[i][j][2]);
          pk.w = f32_to_bf16_rn(acc[i][j][3]);
          *(ushort4*)(vto + ((size_t)bh * HD + d0 + lr) * SEQ + s0) = pk;
        } else {
          ushort* dst = (tt == 0) ? qo : ko;
#pragma unroll
          for (int r = 0; r < 4; ++r)
            dst[((size_t)bh * SEQ + s0 + r) * HD + d0 + lr] = f32_to_bf16_rn(acc[i][j][r]);
        }
      }
    }
  } else {
#pragma unroll
    for (int i = 0; i < 4; ++i) {
#pragma unroll
      for (int j = 0; j < 4; ++j) {
        const int n = n0 + wn * 64 + j * 16 + lr;
        const float bv = bias[n];
#pragma unroll
        for (int r = 0; r < 4; ++r) {
          const int m = m0 + wm * 64 + i * 16 + lq * 4 + r;
          outf[(size_t)m * 512 + n] = acc[i][j][r] + bv;
        }
      }
    }
  }
}

// -------------------------------- fused flash attention ---------------------
// Grid 512 (XCD-swizzled: 8 h-blocks of a (b,qtile) share one XCD's L2 for
// the mask slab). 256 threads = 4 waves; wave w owns q-rows w*32..w*32+31 as
// two 16-row groups. kv tiles of 64, K/V DOUBLE-BUFFERED in LDS -> one
// barrier per tile. Bias: f32 from Btab (L1), folded into mask prefetch.
__global__ __launch_bounds__(256) void attn_fused(
    const ushort* __restrict__ Q, const ushort* __restrict__ Kt,
    const ushort* __restrict__ VT, const float* __restrict__ mask,
    const float* __restrict__ Btab, ushort* __restrict__ Out) {
  __shared__ ushort Ks[2][64 * 72];    // 18432 B
  __shared__ ushort Vs[2][64 * 72];    // 18432 B
  __shared__ ushort Ps[4][32 * 68];    // 17408 B
                                       // total 54272 B

  const int flat = blockIdx.x;         // 512 blocks
  const int xcd = flat & 7;
  const int rr = flat >> 3;            // 0..63
  const int h = rr & 7;
  const int slot = rr >> 3;            // 0..7
  const int g = slot * 8 + xcd;        // 0..63  (b,qt) group
  const int qt = g & 15, b = g >> 4;

  const int bh = b * NHEAD + h;
  const ushort* qh = Q + (size_t)bh * SEQ * HD;
  const ushort* kh = Kt + (size_t)bh * SEQ * HD;
  const ushort* vh = VT + (size_t)bh * HD * SEQ;
  const float* mb = mask + (size_t)b * SEQ * SEQ;
  const float* bt = Btab + h * (2 * SEQ - 1);

  const int t = threadIdx.x;
  const int lane = t & 63, w = t >> 6;       // 4 waves
  const int lr = lane & 15, lq = lane >> 4;
  const int qb0 = qt * 128;
  const int qbaseA = qb0 + w * 32;           // group A rows
  const int qbaseB = qbaseA + 16;            // group B rows

  // Q fragments for both groups — loaded once
  short8 qfA0, qfA1, qfB0, qfB1;
  {
    const ushort* qpA = qh + (size_t)(qbaseA + lr) * HD + lq * 8;
    qfA0 = *(const short8*)qpA;
    qfA1 = *(const short8*)(qpA + 32);
    const ushort* qpB = qh + (size_t)(qbaseB + lr) * HD + lq * 8;
    qfB0 = *(const short8*)qpB;
    qfB1 = *(const short8*)(qpB + 32);
  }

  // mask row pointers (constant-indexed in unrolled loops)
  const float* mrowA[4];
  const float* mrowB[4];
#pragma unroll
  for (int r = 0; r < 4; ++r) {
    mrowA[r] = mb + (size_t)(qbaseA + lq * 4 + r) * SEQ + lr;
    mrowB[r] = mb + (size_t)(qbaseB + lq * 4 + r) * SEQ + lr;
  }
  // bias base pointers: value for (f,r,kv0) = btA[r - kv0 - f*16]
  const float* btA = bt + 2047 + qbaseA + lq * 4 - lr;
  const float* btB = btA + 16;

  float lA0 = 0.f, lA1 = 0.f, lA2 = 0.f, lA3 = 0.f;
  float lB0 = 0.f, lB1 = 0.f, lB2 = 0.f, lB3 = 0.f;
  f32x4 ofA[4], ofB[4];
#pragma unroll
  for (int i = 0; i < 4; ++i) {
    ofA[i] = (f32x4){0.f, 0.f, 0.f, 0.f};
    ofB[i] = (f32x4){0.f, 0.f, 0.f, 0.f};
  }

  const int srow = t >> 3;           // staging row 0..31 (+32 for second half)
  const int sseg = t & 7;            // staging 16B segment

  // per-thread staging source bases
  const ushort* kp = kh + (size_t)srow * HD + sseg * 8;   // + kv*HD (+32*HD)
  const ushort* vp = vh + (size_t)srow * SEQ + sseg * 8;  // + kv (+32*SEQ)

  // prologue: tile0 -> regs -> buf0; then tile1 -> regs
  uint4 kr0 = *(const uint4*)(kp);
  uint4 kr1 = *(const uint4*)(kp + 32 * HD);
  uint4 vr0 = *(const uint4*)(vp);
  uint4 vr1 = *(const uint4*)(vp + 32 * SEQ);
  *(uint4*)&Ks[0][srow * 72 + sseg * 8] = kr0;
  *(uint4*)&Ks[0][(32 + srow) * 72 + sseg * 8] = kr1;
  *(uint4*)&Vs[0][srow * 72 + sseg * 8] = vr0;
  *(uint4*)&Vs[0][(32 + srow) * 72 + sseg * 8] = vr1;
  kr0 = *(const uint4*)(kp + 64 * HD);
  kr1 = *(const uint4*)(kp + 96 * HD);
  vr0 = *(const uint4*)(vp + 64);
  vr1 = *(const uint4*)(vp + 64 + 32 * SEQ);

  // group-A (mask+bias)*log2e prefetch for tile 0
  float mnA[4][4];
#pragma unroll
  for (int f = 0; f < 4; ++f)
#pragma unroll
    for (int r = 0; r < 4; ++r)
      mnA[f][r] = fmaf(mrowA[r][f * 16], L2E, btA[r - f * 16] * L2E);

  for (int it = 0; it < 32; ++it) {
    const int kv0 = it * 64;
    const int cur = it & 1, nxt = cur ^ 1;

    __syncthreads();  // prev writes visible; prev-prev reads of buf[nxt] done

    // write tile it+1 (in regs) into buf[nxt]  (it=31: dead write, never read)
    *(uint4*)&Ks[nxt][srow * 72 + sseg * 8] = kr0;
    *(uint4*)&Ks[nxt][(32 + srow) * 72 + sseg * 8] = kr1;
    *(uint4*)&Vs[nxt][srow * 72 + sseg * 8] = vr0;
    *(uint4*)&Vs[nxt][(32 + srow) * 72 + sseg * 8] = vr1;

    // group-B (mask+bias)*log2e for THIS tile (latency under QK/SM_A)
    float mnB[4][4];
#pragma unroll
    for (int f = 0; f < 4; ++f)
#pragma unroll
      for (int r = 0; r < 4; ++r)
        mnB[f][r] = fmaf(mrowB[r][kv0 + f * 16], L2E,
                         btB[r - kv0 - f * 16] * L2E);

    // issue tile it+2 staging loads (clamped) — latency spans whole iteration
    const int lkv = (it + 2 < 32) ? (it + 2) * 64 : 0;
    kr0 = *(const uint4*)(kp + (size_t)lkv * HD);
    kr1 = *(const uint4*)(kp + (size_t)(lkv + 32) * HD);
    vr0 = *(const uint4*)(vp + lkv);
    vr1 = *(const uint4*)(vp + lkv + 32 * SEQ);

    // QK for BOTH groups — each K fragment read once
    f32x4 sfA[4], sfB[4];
#pragma unroll
    for (int f = 0; f < 4; ++f) {
      const ushort* kfp = &Ks[cur][(f * 16 + lr) * 72 + lq * 8];
      const short8 k0 = *(const short8*)kfp;
      const short8 k1 = *(const short8*)(kfp + 32);
      sfA[f] = (f32x4){0.f, 0.f, 0.f, 0.f};
      sfA[f] = __builtin_amdgcn_mfma_f32_16x16x32_bf16(qfA0, k0, sfA[f], 0, 0, 0);
      sfA[f] = __builtin_amdgcn_mfma_f32_16x16x32_bf16(qfA1, k1, sfA[f], 0, 0, 0);
      sfB[f] = (f32x4){0.f, 0.f, 0.f, 0.f};
      sfB[f] = __builtin_amdgcn_mfma_f32_16x16x32_bf16(qfB0, k0, sfB[f], 0, 0, 0);
      sfB[f] = __builtin_amdgcn_mfma_f32_16x16x32_bf16(qfB1, k1, sfB[f], 0, 0, 0);
    }

    // SM_A: p = exp2(s*scale*log2e + mn); rows 0..15
#pragma unroll
    for (int f = 0; f < 4; ++f) {
#pragma unroll
      for (int r = 0; r < 4; ++r) {
        const float xs = fmaf(sfA[f][r], 0.18033688f, mnA[f][r]);
        const float p = __builtin_amdgcn_exp2f(xs);
        if (r == 0) lA0 += p; else if (r == 1) lA1 += p;
        else if (r == 2) lA2 += p; else lA3 += p;
        const unsigned u = __builtin_bit_cast(unsigned, p);
        Ps[w][(lq * 4 + r) * 68 + f * 16 + lr] =
            (unsigned short)((u + 0x8000u) >> 16);
      }
    }

    // group-A (mask+bias) prefetch for NEXT tile (after last use), clamped
    const int mkv = (it + 1 < 32) ? (it + 1) * 64 : 0;
#pragma unroll
    for (int f = 0; f < 4; ++f)
#pragma unroll
      for (int r = 0; r < 4; ++r)
        mnA[f][r] = fmaf(mrowA[r][mkv + f * 16], L2E,
                         btA[r - mkv - f * 16] * L2E);

    // SM_B: rows 16..31
#pragma unroll
    for (int f = 0; f < 4; ++f) {
#pragma unroll
      for (int r = 0; r < 4; ++r) {
        const float xs = fmaf(sfB[f][r], 0.18033688f, mnB[f][r]);
        const float p = __builtin_amdgcn_exp2f(xs);
        if (r == 0) lB0 += p; else if (r == 1) lB1 += p;
        else if (r == 2) lB2 += p; else lB3 += p;
        const unsigned u = __builtin_bit_cast(unsigned, p);
        Ps[w][(16 + lq * 4 + r) * 68 + f * 16 + lr] =
            (unsigned short)((u + 0x8000u) >> 16);
      }
    }

    // PV for BOTH groups — each V fragment read once
#pragma unroll
    for (int ks = 0; ks < 2; ++ks) {
      union { uint2 u[2]; short8 s; } puA, puB;
      const int pbase = ks * 32 + lq * 8;
      puA.u[0] = *(const uint2*)&Ps[w][lr * 68 + pbase];
      puA.u[1] = *(const uint2*)&Ps[w][lr * 68 + pbase + 4];
      puB.u[0] = *(const uint2*)&Ps[w][(16 + lr) * 68 + pbase];
      puB.u[1] = *(const uint2*)&Ps[w][(16 + lr) * 68 + pbase + 4];
#pragma unroll
      for (int hf = 0; hf < 4; ++hf) {
        const short8 vf =
            *(const short8*)&Vs[cur][(hf * 16 + lr) * 72 + ks * 32 + lq * 8];
        ofA[hf] = __builtin_amdgcn_mfma_f32_16x16x32_bf16(puA.s, vf, ofA[hf], 0, 0, 0);
        ofB[hf] = __builtin_amdgcn_mfma_f32_16x16x32_bf16(puB.s, vf, ofB[hf], 0, 0, 0);
      }
    }
  }

  // cross-lane l reductions (16-lane groups), normalize, write both groups
  float lA[4] = {lA0, lA1, lA2, lA3};
  float lB[4] = {lB0, lB1, lB2, lB3};
#pragma unroll
  for (int r = 0; r < 4; ++r) {
    float v = lA[r];
    v += __shfl_xor(v, 1); v += __shfl_xor(v, 2);
    v += __shfl_xor(v, 4); v += __shfl_xor(v, 8);
    lA[r] = v;
    float u = lB[r];
    u += __shfl_xor(u, 1); u += __shfl_xor(u, 2);
    u += __shfl_xor(u, 4); u += __shfl_xor(u, 8);
    lB[r] = u;
  }
#pragma unroll
  for (int r = 0; r < 4; ++r) {
    const float invA = 1.0f / lA[r];
    const int qrA = qbaseA + lq * 4 + r;
    ushort* opA = Out + ((size_t)(b * SEQ + qrA)) * CDIM + h * HD;
#pragma unroll
    for (int hf = 0; hf < 4; ++hf) opA[hf * 16 + lr] = f32_to_bf16_rn(ofA[hf][r] * invA);
    const float invB = 1.0f / lB[r];
    const int qrB = qbaseB + lq * 4 + r;
    ushort* opB = Out + ((size_t)(b * SEQ + qrB)) * CDIM + h * HD;
#pragma unroll
    for (int hf = 0; hf < 4; ++hf) opB[hf * 16 + lr] = f32_to_bf16_rn(ofB[hf][r] * invB);
  }
}

// ---------------------------------------------------------------------------
extern "C" void kernel_launch(void* const* d_in, const int* in_sizes, int n_in,
                              void* d_out, int out_size, void* d_ws, size_t ws_size,
                              hipStream_t stream) {
  const float* x     = (const float*)d_in[0];
  const float* mask  = (const float*)d_in[1];
  const float* Wqkv  = (const float*)d_in[2];
  const float* Btab  = (const float*)d_in[3];
  const float* Wproj = (const float*)d_in[4];
  const float* bproj = (const float*)d_in[5];
  float* out = (float*)d_out;

  char* ws = (char*)d_ws;
  const size_t SZ_X   = (size_t)NBATCH * SEQ * CDIM;
  const size_t SZ_QKV = (size_t)3 * CDIM * CDIM;
  const size_t SZ_PRJ = (size_t)CDIM * CDIM;
  const size_t SZ_HD  = (size_t)NBATCH * NHEAD * SEQ * HD;

  ushort* xb    = (ushort*)ws; ws += SZ_X * 2;
  ushort* wqkvb = (ushort*)ws; ws += SZ_QKV * 2;
  ushort* wprjb = (ushort*)ws; ws += SZ_PRJ * 2;
  ushort* qb    = (ushort*)ws; ws += SZ_HD * 2;
  ushort* kb    = (ushort*)ws; ws += SZ_HD * 2;
  ushort* vtb   = (ushort*)ws; ws += SZ_HD * 2;
  ushort* aob   = (ushort*)ws; ws += SZ_X * 2;

  {
    int n4 = (int)(SZ_X / 4);
    int g = (n4 + 255) / 256; if (g > 4096) g = 4096;
    cvt_f32_bf16<<<g, 256, 0, stream>>>(x, xb, n4);
  }
  {
    int n4 = (int)(SZ_QKV / 4);
    cvt_f32_bf16<<<(n4 + 255) / 256, 256, 0, stream>>>(Wqkv, wqkvb, n4);
  }
  {
    int n4 = (int)(SZ_PRJ / 4);
    cvt_f32_bf16<<<(n4 + 255) / 256, 256, 0, stream>>>(Wproj, wprjb, n4);
  }

  // QKV: M=8192, N=1536, K=512
  gemm_nt<0><<<dim3(12, 64), 256, 0, stream>>>(xb, wqkvb, qb, kb, vtb, nullptr, nullptr);

  // fused attention (1D swizzled grid, 256-thread blocks, 128 q-rows each)
  attn_fused<<<dim3(512), 256, 0, stream>>>(qb, kb, vtb, mask, Btab, aob);

  // proj: M=8192, N=512, K=512, +bias, f32 out
  gemm_nt<1><<<dim3(4, 64), 256, 0, stream>>>(aob, wprjb, nullptr, nullptr, nullptr, bproj, out);
}

// Round 10
// 157.054 us; speedup vs baseline: 1.5627x; 1.5627x over previous
//
#include <hip/hip_runtime.h>

// ---------------------------------------------------------------------------
// RelativeAttention: out = softmax(QK^T*scale + relbias + mask) V, + proj
// B=4 H=8 N=2048 C=512 hd=64.  bf16 MFMA pipeline, f32 accum.
// R10: revert R9's fold-at-prefetch (it serialized the mask loads: 112->276).
//      Swap QK operands: S = mfma(K,Q) puts kv r-contiguous per lane ->
//      mask loads become float4 (32 scalar->8 vec), Ps writes become packed
//      ds_write_b64 (32->8), l becomes scalar/group. Q/K/V loads, Ps-as-
//      transpose and PV step unchanged from R8. Bias stays in Bw LDS (bf16).
// ---------------------------------------------------------------------------

typedef __attribute__((ext_vector_type(8))) short short8;   // 8 bf16 (4 VGPR)
typedef __attribute__((ext_vector_type(4))) float f32x4;    // MFMA C/D

#define SEQ   2048
#define NHEAD 8
#define NBATCH 4
#define HD    64
#define CDIM  512
#define L2E   1.44269504f

__device__ __forceinline__ unsigned short f32_to_bf16_rn(float f) {
  unsigned u = __builtin_bit_cast(unsigned, f);
  u += 0x7FFFu + ((u >> 16) & 1u);
  return (unsigned short)(u >> 16);
}

// -------------------------------- f32 -> bf16 convert (vectorized) ----------
__global__ __launch_bounds__(256) void cvt_f32_bf16(const float* __restrict__ in,
                                                    ushort* __restrict__ out, int n4) {
  int i = blockIdx.x * 256 + threadIdx.x;
  const int stride = gridDim.x * 256;
  for (; i < n4; i += stride) {
    float4 v = reinterpret_cast<const float4*>(in)[i];
    ushort4 o;
    o.x = f32_to_bf16_rn(v.x);
    o.y = f32_to_bf16_rn(v.y);
    o.z = f32_to_bf16_rn(v.z);
    o.w = f32_to_bf16_rn(v.w);
    reinterpret_cast<ushort4*>(out)[i] = o;
  }
}

// -------------------------------- NT GEMM: C = A(MxK) * B(NxK)^T ------------
// 128x128 tile, 4 waves (2x2), each wave 64x64 = 4x4 frags of 16x16x32 bf16.
// MODE 0: QKV epilogue -> scatter q[b,h,n,d], k[b,h,n,d], vT[b,h,d,n] (bf16)
// MODE 1: proj epilogue -> f32 out += bias
template <int MODE>
__global__ __launch_bounds__(256) void gemm_nt(
    const ushort* __restrict__ A, const ushort* __restrict__ Bm,
    ushort* __restrict__ qo, ushort* __restrict__ ko, ushort* __restrict__ vto,
    const float* __restrict__ bias, float* __restrict__ outf) {
  const int K = 512;
  __shared__ ushort As[128 * 40];
  __shared__ ushort Bs[128 * 40];

  const int t = threadIdx.x;
  const int bn = blockIdx.x, bm = blockIdx.y;
  const int lane = t & 63, w = t >> 6;
  const int wm = w >> 1, wn = w & 1;
  const int lr = lane & 15, lq = lane >> 4;
  const int m0 = bm * 128, n0 = bn * 128;

  f32x4 acc[4][4];
#pragma unroll
  for (int i = 0; i < 4; ++i)
#pragma unroll
    for (int j = 0; j < 4; ++j) acc[i][j] = (f32x4){0.f, 0.f, 0.f, 0.f};

  for (int kt = 0; kt < K; kt += 32) {
#pragma unroll
    for (int p = 0; p < 2; ++p) {
      const int flat = p * 256 + t;
      const int row = flat >> 2, seg = flat & 3;
      *(uint4*)&As[row * 40 + seg * 8] =
          *(const uint4*)(A + (size_t)(m0 + row) * K + kt + seg * 8);
      *(uint4*)&Bs[row * 40 + seg * 8] =
          *(const uint4*)(Bm + (size_t)(n0 + row) * K + kt + seg * 8);
    }
    __syncthreads();

    short8 af[4], bf[4];
#pragma unroll
    for (int i = 0; i < 4; ++i) {
      af[i] = *(const short8*)&As[(wm * 64 + i * 16 + lr) * 40 + lq * 8];
      bf[i] = *(const short8*)&Bs[(wn * 64 + i * 16 + lr) * 40 + lq * 8];
    }
#pragma unroll
    for (int i = 0; i < 4; ++i)
#pragma unroll
      for (int j = 0; j < 4; ++j)
        acc[i][j] = __builtin_amdgcn_mfma_f32_16x16x32_bf16(af[i], bf[j], acc[i][j], 0, 0, 0);
    __syncthreads();
  }

  if constexpr (MODE == 0) {
#pragma unroll
    for (int i = 0; i < 4; ++i) {
      const int mbase = m0 + wm * 64 + i * 16 + lq * 4;  // + r
      const int bb = mbase >> 11;
      const int s0 = mbase & 2047;
#pragma unroll
      for (int j = 0; j < 4; ++j) {
        const int nb = n0 + wn * 64 + j * 16;
        const int tt = nb >> 9;
        const int hh = (nb >> 6) & 7;
        const int d0 = nb & 63;
        const int bh = bb * NHEAD + hh;
        if (tt == 2) {
          ushort4 pk;
          pk.x = f32_to_bf16_rn(acc[i][j][0]);
          pk.y = f32_to_bf16_rn(acc[i][j][1]);
          pk.z = f32_to_bf16_rn(acc[i][j][2]);
          pk.w = f32_to_bf16_rn(acc[i][j][3]);
          *(ushort4*)(vto + ((size_t)bh * HD + d0 + lr) * SEQ + s0) = pk;
        } else {
          ushort* dst = (tt == 0) ? qo : ko;
#pragma unroll
          for (int r = 0; r < 4; ++r)
            dst[((size_t)bh * SEQ + s0 + r) * HD + d0 + lr] = f32_to_bf16_rn(acc[i][j][r]);
        }
      }
    }
  } else {
#pragma unroll
    for (int i = 0; i < 4; ++i) {
#pragma unroll
      for (int j = 0; j < 4; ++j) {
        const int n = n0 + wn * 64 + j * 16 + lr;
        const float bv = bias[n];
#pragma unroll
        for (int r = 0; r < 4; ++r) {
          const int m = m0 + wm * 64 + i * 16 + lq * 4 + r;
          outf[(size_t)m * 512 + n] = acc[i][j][r] + bv;
        }
      }
    }
  }
}

// -------------------------------- fused flash attention ---------------------
// Grid 512 (XCD-swizzled). 256 threads = 4 waves; wave w owns q-rows
// w*32..w*32+31 as two 16-row groups. kv tiles of 64, K/V double-buffered in
// LDS, one barrier per tile. SWAPPED QK: S=mfma(K,Q) -> lane owns ONE q-row
// (lr) and 16 r-contiguous kv slots -> float4 mask loads, b64 Ps writes,
// scalar l. All prefetches are LOAD-ONLY (R9 lesson).
__global__ __launch_bounds__(256) void attn_fused(
    const ushort* __restrict__ Q, const ushort* __restrict__ Kt,
    const ushort* __restrict__ VT, const float* __restrict__ mask,
    const float* __restrict__ Btab, ushort* __restrict__ Out) {
  __shared__ ushort Ks[2][64 * 72];    // 18432 B
  __shared__ ushort Vs[2][64 * 72];    // 18432 B
  __shared__ ushort Ps[4][32 * 72];    // 18432 B  (rows: A 0-15, B 16-31)
  __shared__ ushort Bw[2176];          //  4352 B  bias*log2e, bf16
                                       // total 59648 B -> 2 blocks/CU

  const int flat = blockIdx.x;         // 512 blocks
  const int xcd = flat & 7;
  const int rr = flat >> 3;            // 0..63
  const int h = rr & 7;
  const int slot = rr >> 3;            // 0..7
  const int g = slot * 8 + xcd;        // 0..63  (b,qt) group
  const int qt = g & 15, b = g >> 4;

  const int bh = b * NHEAD + h;
  const ushort* qh = Q + (size_t)bh * SEQ * HD;
  const ushort* kh = Kt + (size_t)bh * SEQ * HD;
  const ushort* vh = VT + (size_t)bh * HD * SEQ;
  const float* mb = mask + (size_t)b * SEQ * SEQ;
  const float* bt = Btab + h * (2 * SEQ - 1);

  const int t = threadIdx.x;
  const int lane = t & 63, w = t >> 6;       // 4 waves
  const int lr = lane & 15, lq = lane >> 4;
  const int qb0 = qt * 128;
  const int qbaseA = qb0 + w * 32;           // group A rows (+lr)
  const int qbaseB = qbaseA + 16;            // group B rows (+lr)

  // stage bias window [qb0, qb0+2174] once, bf16, prescaled by log2(e)
  for (int i = t; i < 2175; i += 256)
    Bw[i] = f32_to_bf16_rn(bt[qb0 + i] * L2E);

  // Q fragments (same registers serve as the MFMA B-operand after the swap)
  short8 qfA0, qfA1, qfB0, qfB1;
  {
    const ushort* qpA = qh + (size_t)(qbaseA + lr) * HD + lq * 8;
    qfA0 = *(const short8*)qpA;
    qfA1 = *(const short8*)(qpA + 32);
    const ushort* qpB = qh + (size_t)(qbaseB + lr) * HD + lq * 8;
    qfB0 = *(const short8*)qpB;
    qfB1 = *(const short8*)(qpB + 32);
  }

  // mask vector pointers: lane's q-row, element offset 4*lq; +kv0+16f at use
  const float* mvA = mb + (size_t)(qbaseA + lr) * SEQ + 4 * lq;
  const float* mvB = mb + (size_t)(qbaseB + lr) * SEQ + 4 * lq;
  // Bw local index base: idx(f,r,kv0) = bwA0 - kv0 - 16f - r
  const int bwA0 = w * 32 + lr - 4 * lq + 2047;
  const int bwB0 = bwA0 + 16;

  float lAa = 0.f, lAb = 0.f, lBa = 0.f, lBb = 0.f;  // 2 partials per group
  f32x4 ofA[4], ofB[4];
#pragma unroll
  for (int i = 0; i < 4; ++i) {
    ofA[i] = (f32x4){0.f, 0.f, 0.f, 0.f};
    ofB[i] = (f32x4){0.f, 0.f, 0.f, 0.f};
  }

  const int srow = t >> 3;           // staging row 0..31 (+32 for second half)
  const int sseg = t & 7;            // staging 16B segment

  // per-thread staging source bases
  const ushort* kp = kh + (size_t)srow * HD + sseg * 8;   // + kv*HD (+32*HD)
  const ushort* vp = vh + (size_t)srow * SEQ + sseg * 8;  // + kv (+32*SEQ)

  // prologue: tile0 -> regs -> buf0; then tile1 -> regs
  uint4 kr0 = *(const uint4*)(kp);
  uint4 kr1 = *(const uint4*)(kp + 32 * HD);
  uint4 vr0 = *(const uint4*)(vp);
  uint4 vr1 = *(const uint4*)(vp + 32 * SEQ);
  *(uint4*)&Ks[0][srow * 72 + sseg * 8] = kr0;
  *(uint4*)&Ks[0][(32 + srow) * 72 + sseg * 8] = kr1;
  *(uint4*)&Vs[0][srow * 72 + sseg * 8] = vr0;
  *(uint4*)&Vs[0][(32 + srow) * 72 + sseg * 8] = vr1;
  kr0 = *(const uint4*)(kp + 64 * HD);
  kr1 = *(const uint4*)(kp + 96 * HD);
  vr0 = *(const uint4*)(vp + 64);
  vr1 = *(const uint4*)(vp + 64 + 32 * SEQ);

  // group-A mask prefetch for tile 0 (LOAD-ONLY)
  float4 mnA[4];
#pragma unroll
  for (int f = 0; f < 4; ++f) mnA[f] = *(const float4*)(mvA + f * 16);

  for (int it = 0; it < 32; ++it) {
    const int kv0 = it * 64;
    const int cur = it & 1, nxt = cur ^ 1;

    __syncthreads();  // prev writes visible; prev-prev reads of buf[nxt] done

    // write tile it+1 (in regs) into buf[nxt]  (it=31: dead write, never read)
    *(uint4*)&Ks[nxt][srow * 72 + sseg * 8] = kr0;
    *(uint4*)&Ks[nxt][(32 + srow) * 72 + sseg * 8] = kr1;
    *(uint4*)&Vs[nxt][srow * 72 + sseg * 8] = vr0;
    *(uint4*)&Vs[nxt][(32 + srow) * 72 + sseg * 8] = vr1;

    // group-B mask loads for THIS tile (LOAD-ONLY; wait sinks to SM_B use)
    float4 mnB[4];
#pragma unroll
    for (int f = 0; f < 4; ++f)
      mnB[f] = *(const float4*)(mvB + kv0 + f * 16);

    // issue tile it+2 staging loads (clamped) — latency spans whole iteration
    const int lkv = (it + 2 < 32) ? (it + 2) * 64 : 0;
    kr0 = *(const uint4*)(kp + (size_t)lkv * HD);
    kr1 = *(const uint4*)(kp + (size_t)(lkv + 32) * HD);
    vr0 = *(const uint4*)(vp + lkv);
    vr1 = *(const uint4*)(vp + lkv + 32 * SEQ);

    // QK (swapped): sf[f][r] = S[qrow = lr][kv = kv0 + 16f + 4lq + r]
    f32x4 sfA[4], sfB[4];
#pragma unroll
    for (int f = 0; f < 4; ++f) {
      const ushort* kfp = &Ks[cur][(f * 16 + lr) * 72 + lq * 8];
      const short8 k0 = *(const short8*)kfp;
      const short8 k1 = *(const short8*)(kfp + 32);
      sfA[f] = (f32x4){0.f, 0.f, 0.f, 0.f};
      sfA[f] = __builtin_amdgcn_mfma_f32_16x16x32_bf16(k0, qfA0, sfA[f], 0, 0, 0);
      sfA[f] = __builtin_amdgcn_mfma_f32_16x16x32_bf16(k1, qfA1, sfA[f], 0, 0, 0);
      sfB[f] = (f32x4){0.f, 0.f, 0.f, 0.f};
      sfB[f] = __builtin_amdgcn_mfma_f32_16x16x32_bf16(k0, qfB0, sfB[f], 0, 0, 0);
      sfB[f] = __builtin_amdgcn_mfma_f32_16x16x32_bf16(k1, qfB1, sfB[f], 0, 0, 0);
    }

    // SM_A: p = exp2(s*scale*log2e + mask*log2e + bw); pack 4 -> b64 write
#pragma unroll
    for (int f = 0; f < 4; ++f) {
      const int ibA = bwA0 - kv0 - 16 * f;
      unsigned up0, up1;
#pragma unroll
      for (int r = 0; r < 4; ++r) {
        const float bwv =
            __builtin_bit_cast(float, ((unsigned)Bw[ibA - r]) << 16);
        const float xs = fmaf(sfA[f][r], 0.18033688f,
                              fmaf((&mnA[f].x)[r], L2E, bwv));
        const float p = __builtin_amdgcn_exp2f(xs);
        if (f & 1) lAb += p; else lAa += p;
        const unsigned hh = (__builtin_bit_cast(unsigned, p) + 0x8000u) >> 16;
        if (r == 0) up0 = hh;
        else if (r == 1) up0 |= hh << 16;
        else if (r == 2) up1 = hh;
        else up1 |= hh << 16;
      }
      uint2 pk; pk.x = up0; pk.y = up1;
      *(uint2*)&Ps[w][lr * 72 + 16 * f + 4 * lq] = pk;
    }

    // group-A mask prefetch for NEXT tile (LOAD-ONLY), clamped
    const int mkv = (it + 1 < 32) ? (it + 1) * 64 : 0;
#pragma unroll
    for (int f = 0; f < 4; ++f)
      mnA[f] = *(const float4*)(mvA + mkv + f * 16);

    // SM_B: rows 16..31
#pragma unroll
    for (int f = 0; f < 4; ++f) {
      const int ibB = bwB0 - kv0 - 16 * f;
      unsigned up0, up1;
#pragma unroll
      for (int r = 0; r < 4; ++r) {
        const float bwv =
            __builtin_bit_cast(float, ((unsigned)Bw[ibB - r]) << 16);
        const float xs = fmaf(sfB[f][r], 0.18033688f,
                              fmaf((&mnB[f].x)[r], L2E, bwv));
        const float p = __builtin_amdgcn_exp2f(xs);
        if (f & 1) lBb += p; else lBa += p;
        const unsigned hh = (__builtin_bit_cast(unsigned, p) + 0x8000u) >> 16;
        if (r == 0) up0 = hh;
        else if (r == 1) up0 |= hh << 16;
        else if (r == 2) up1 = hh;
        else up1 |= hh << 16;
      }
      uint2 pk; pk.x = up0; pk.y = up1;
      *(uint2*)&Ps[w][(16 + lr) * 72 + 16 * f + 4 * lq] = pk;
    }

    // PV for BOTH groups — unchanged semantics; single b128 Ps reads
#pragma unroll
    for (int ks = 0; ks < 2; ++ks) {
      union { uint4 u; short8 s; } puA, puB;
      puA.u = *(const uint4*)&Ps[w][lr * 72 + ks * 32 + lq * 8];
      puB.u = *(const uint4*)&Ps[w][(16 + lr) * 72 + ks * 32 + lq * 8];
#pragma unroll
      for (int hf = 0; hf < 4; ++hf) {
        const short8 vf =
            *(const short8*)&Vs[cur][(hf * 16 + lr) * 72 + ks * 32 + lq * 8];
        ofA[hf] = __builtin_amdgcn_mfma_f32_16x16x32_bf16(puA.s, vf, ofA[hf], 0, 0, 0);
        ofB[hf] = __builtin_amdgcn_mfma_f32_16x16x32_bf16(puB.s, vf, ofB[hf], 0, 0, 0);
      }
    }
  }

  // l: sum across the 4 lq groups (lanes xor 16, 32); lane then holds
  // l[qrow = lr] of its group. Redistribute so (lq,r) gets l[lq*4+r].
  float vA = lAa + lAb;
  vA += __shfl_xor(vA, 16); vA += __shfl_xor(vA, 32);
  float vB = lBa + lBb;
  vB += __shfl_xor(vB, 16); vB += __shfl_xor(vB, 32);

#pragma unroll
  for (int r = 0; r < 4; ++r) {
    const float invA = 1.0f / __shfl(vA, (lane & 48) | (lq * 4 + r));
    const int qrA = qbaseA + lq * 4 + r;
    ushort* opA = Out + ((size_t)(b * SEQ + qrA)) * CDIM + h * HD;
#pragma unroll
    for (int hf = 0; hf < 4; ++hf) opA[hf * 16 + lr] = f32_to_bf16_rn(ofA[hf][r] * invA);
    const float invB = 1.0f / __shfl(vB, (lane & 48) | (lq * 4 + r));
    const int qrB = qbaseB + lq * 4 + r;
    ushort* opB = Out + ((size_t)(b * SEQ + qrB)) * CDIM + h * HD;
#pragma unroll
    for (int hf = 0; hf < 4; ++hf) opB[hf * 16 + lr] = f32_to_bf16_rn(ofB[hf][r] * invB);
  }
}

// ---------------------------------------------------------------------------
extern "C" void kernel_launch(void* const* d_in, const int* in_sizes, int n_in,
                              void* d_out, int out_size, void* d_ws, size_t ws_size,
                              hipStream_t stream) {
  const float* x     = (const float*)d_in[0];
  const float* mask  = (const float*)d_in[1];
  const float* Wqkv  = (const float*)d_in[2];
  const float* Btab  = (const float*)d_in[3];
  const float* Wproj = (const float*)d_in[4];
  const float* bproj = (const float*)d_in[5];
  float* out = (float*)d_out;

  char* ws = (char*)d_ws;
  const size_t SZ_X   = (size_t)NBATCH * SEQ * CDIM;
  const size_t SZ_QKV = (size_t)3 * CDIM * CDIM;
  const size_t SZ_PRJ = (size_t)CDIM * CDIM;
  const size_t SZ_HD  = (size_t)NBATCH * NHEAD * SEQ * HD;

  ushort* xb    = (ushort*)ws; ws += SZ_X * 2;
  ushort* wqkvb = (ushort*)ws; ws += SZ_QKV * 2;
  ushort* wprjb = (ushort*)ws; ws += SZ_PRJ * 2;
  ushort* qb    = (ushort*)ws; ws += SZ_HD * 2;
  ushort* kb    = (ushort*)ws; ws += SZ_HD * 2;
  ushort* vtb   = (ushort*)ws; ws += SZ_HD * 2;
  ushort* aob   = (ushort*)ws; ws += SZ_X * 2;

  {
    int n4 = (int)(SZ_X / 4);
    int g = (n4 + 255) / 256; if (g > 4096) g = 4096;
    cvt_f32_bf16<<<g, 256, 0, stream>>>(x, xb, n4);
  }
  {
    int n4 = (int)(SZ_QKV / 4);
    cvt_f32_bf16<<<(n4 + 255) / 256, 256, 0, stream>>>(Wqkv, wqkvb, n4);
  }
  {
    int n4 = (int)(SZ_PRJ / 4);
    cvt_f32_bf16<<<(n4 + 255) / 256, 256, 0, stream>>>(Wproj, wprjb, n4);
  }

  // QKV: M=8192, N=1536, K=512
  gemm_nt<0><<<dim3(12, 64), 256, 0, stream>>>(xb, wqkvb, qb, kb, vtb, nullptr, nullptr);

  // fused attention (1D swizzled grid, 256-thread blocks, 128 q-rows each)
  attn_fused<<<dim3(512), 256, 0, stream>>>(qb, kb, vtb, mask, Btab, aob);

  // proj: M=8192, N=512, K=512, +bias, f32 out
  gemm_nt<1><<<dim3(4, 64), 256, 0, stream>>>(aob, wprjb, nullptr, nullptr, nullptr, bproj, out);
}

// Round 11
// 145.731 us; speedup vs baseline: 1.6841x; 1.0777x over previous
//
#include <hip/hip_runtime.h>

// ---------------------------------------------------------------------------
// RelativeAttention: out = softmax(QK^T*scale + relbias + mask) V, + proj
// B=4 H=8 N=2048 C=512 hd=64.  bf16 MFMA pipeline, f32 accum.
// R11: bias off the LDS pipe (it was 186 of 522 LDS-cy/wave-tile + the worst
//      bank pattern). The R10 operand swap makes lane bias indices
//      r-CONTIGUOUS -> one float4 global load per f (L1-resident Btab),
//      prefetched LOAD-ONLY like the mask (R9 lesson: no arithmetic at the
//      issue site), folded at use: (mask+bias)*log2e. Bw table deleted.
// ---------------------------------------------------------------------------

typedef __attribute__((ext_vector_type(8))) short short8;   // 8 bf16 (4 VGPR)
typedef __attribute__((ext_vector_type(4))) float f32x4;    // MFMA C/D

#define SEQ   2048
#define NHEAD 8
#define NBATCH 4
#define HD    64
#define CDIM  512
#define L2E   1.44269504f

__device__ __forceinline__ unsigned short f32_to_bf16_rn(float f) {
  unsigned u = __builtin_bit_cast(unsigned, f);
  u += 0x7FFFu + ((u >> 16) & 1u);
  return (unsigned short)(u >> 16);
}

// -------------------------------- f32 -> bf16 convert (vectorized) ----------
__global__ __launch_bounds__(256) void cvt_f32_bf16(const float* __restrict__ in,
                                                    ushort* __restrict__ out, int n4) {
  int i = blockIdx.x * 256 + threadIdx.x;
  const int stride = gridDim.x * 256;
  for (; i < n4; i += stride) {
    float4 v = reinterpret_cast<const float4*>(in)[i];
    ushort4 o;
    o.x = f32_to_bf16_rn(v.x);
    o.y = f32_to_bf16_rn(v.y);
    o.z = f32_to_bf16_rn(v.z);
    o.w = f32_to_bf16_rn(v.w);
    reinterpret_cast<ushort4*>(out)[i] = o;
  }
}

// -------------------------------- NT GEMM: C = A(MxK) * B(NxK)^T ------------
// 128x128 tile, 4 waves (2x2), each wave 64x64 = 4x4 frags of 16x16x32 bf16.
// MODE 0: QKV epilogue -> scatter q[b,h,n,d], k[b,h,n,d], vT[b,h,d,n] (bf16)
// MODE 1: proj epilogue -> f32 out += bias
template <int MODE>
__global__ __launch_bounds__(256) void gemm_nt(
    const ushort* __restrict__ A, const ushort* __restrict__ Bm,
    ushort* __restrict__ qo, ushort* __restrict__ ko, ushort* __restrict__ vto,
    const float* __restrict__ bias, float* __restrict__ outf) {
  const int K = 512;
  __shared__ ushort As[128 * 40];
  __shared__ ushort Bs[128 * 40];

  const int t = threadIdx.x;
  const int bn = blockIdx.x, bm = blockIdx.y;
  const int lane = t & 63, w = t >> 6;
  const int wm = w >> 1, wn = w & 1;
  const int lr = lane & 15, lq = lane >> 4;
  const int m0 = bm * 128, n0 = bn * 128;

  f32x4 acc[4][4];
#pragma unroll
  for (int i = 0; i < 4; ++i)
#pragma unroll
    for (int j = 0; j < 4; ++j) acc[i][j] = (f32x4){0.f, 0.f, 0.f, 0.f};

  for (int kt = 0; kt < K; kt += 32) {
#pragma unroll
    for (int p = 0; p < 2; ++p) {
      const int flat = p * 256 + t;
      const int row = flat >> 2, seg = flat & 3;
      *(uint4*)&As[row * 40 + seg * 8] =
          *(const uint4*)(A + (size_t)(m0 + row) * K + kt + seg * 8);
      *(uint4*)&Bs[row * 40 + seg * 8] =
          *(const uint4*)(Bm + (size_t)(n0 + row) * K + kt + seg * 8);
    }
    __syncthreads();

    short8 af[4], bf[4];
#pragma unroll
    for (int i = 0; i < 4; ++i) {
      af[i] = *(const short8*)&As[(wm * 64 + i * 16 + lr) * 40 + lq * 8];
      bf[i] = *(const short8*)&Bs[(wn * 64 + i * 16 + lr) * 40 + lq * 8];
    }
#pragma unroll
    for (int i = 0; i < 4; ++i)
#pragma unroll
      for (int j = 0; j < 4; ++j)
        acc[i][j] = __builtin_amdgcn_mfma_f32_16x16x32_bf16(af[i], bf[j], acc[i][j], 0, 0, 0);
    __syncthreads();
  }

  if constexpr (MODE == 0) {
#pragma unroll
    for (int i = 0; i < 4; ++i) {
      const int mbase = m0 + wm * 64 + i * 16 + lq * 4;  // + r
      const int bb = mbase >> 11;
      const int s0 = mbase & 2047;
#pragma unroll
      for (int j = 0; j < 4; ++j) {
        const int nb = n0 + wn * 64 + j * 16;
        const int tt = nb >> 9;
        const int hh = (nb >> 6) & 7;
        const int d0 = nb & 63;
        const int bh = bb * NHEAD + hh;
        if (tt == 2) {
          ushort4 pk;
          pk.x = f32_to_bf16_rn(acc[i][j][0]);
          pk.y = f32_to_bf16_rn(acc[i][j][1]);
          pk.z = f32_to_bf16_rn(acc[i][j][2]);
          pk.w = f32_to_bf16_rn(acc[i][j][3]);
          *(ushort4*)(vto + ((size_t)bh * HD + d0 + lr) * SEQ + s0) = pk;
        } else {
          ushort* dst = (tt == 0) ? qo : ko;
#pragma unroll
          for (int r = 0; r < 4; ++r)
            dst[((size_t)bh * SEQ + s0 + r) * HD + d0 + lr] = f32_to_bf16_rn(acc[i][j][r]);
        }
      }
    }
  } else {
#pragma unroll
    for (int i = 0; i < 4; ++i) {
#pragma unroll
      for (int j = 0; j < 4; ++j) {
        const int n = n0 + wn * 64 + j * 16 + lr;
        const float bv = bias[n];
#pragma unroll
        for (int r = 0; r < 4; ++r) {
          const int m = m0 + wm * 64 + i * 16 + lq * 4 + r;
          outf[(size_t)m * 512 + n] = acc[i][j][r] + bv;
        }
      }
    }
  }
}

// -------------------------------- fused flash attention ---------------------
// Grid 512 (XCD-swizzled). 256 threads = 4 waves; wave w owns q-rows
// w*32..w*32+31 as two 16-row groups. kv tiles of 64, K/V double-buffered in
// LDS, one barrier per tile. SWAPPED QK: S=mfma(K,Q) -> lane owns ONE q-row
// (lr), kv r-contiguous -> float4 mask AND float4 bias loads (both LOAD-ONLY
// prefetched), b64 Ps writes, scalar l. Bias folded at USE site only.
__global__ __launch_bounds__(256) void attn_fused(
    const ushort* __restrict__ Q, const ushort* __restrict__ Kt,
    const ushort* __restrict__ VT, const float* __restrict__ mask,
    const float* __restrict__ Btab, ushort* __restrict__ Out) {
  __shared__ ushort Ks[2][64 * 72];    // 18432 B
  __shared__ ushort Vs[2][64 * 72];    // 18432 B
  __shared__ ushort Ps[4][32 * 72];    // 18432 B  (rows: A 0-15, B 16-31)
                                       // total 55296 B -> 2 blocks/CU

  const int flat = blockIdx.x;         // 512 blocks
  const int xcd = flat & 7;
  const int rr = flat >> 3;            // 0..63
  const int h = rr & 7;
  const int slot = rr >> 3;            // 0..7
  const int g = slot * 8 + xcd;        // 0..63  (b,qt) group
  const int qt = g & 15, b = g >> 4;

  const int bh = b * NHEAD + h;
  const ushort* qh = Q + (size_t)bh * SEQ * HD;
  const ushort* kh = Kt + (size_t)bh * SEQ * HD;
  const ushort* vh = VT + (size_t)bh * HD * SEQ;
  const float* mb = mask + (size_t)b * SEQ * SEQ;
  const float* bt = Btab + h * (2 * SEQ - 1);

  const int t = threadIdx.x;
  const int lane = t & 63, w = t >> 6;       // 4 waves
  const int lr = lane & 15, lq = lane >> 4;
  const int qb0 = qt * 128;
  const int qbaseA = qb0 + w * 32;           // group A rows (+lr)
  const int qbaseB = qbaseA + 16;            // group B rows (+lr)

  // Q fragments (serve as the MFMA B-operand after the swap)
  short8 qfA0, qfA1, qfB0, qfB1;
  {
    const ushort* qpA = qh + (size_t)(qbaseA + lr) * HD + lq * 8;
    qfA0 = *(const short8*)qpA;
    qfA1 = *(const short8*)(qpA + 32);
    const ushort* qpB = qh + (size_t)(qbaseB + lr) * HD + lq * 8;
    qfB0 = *(const short8*)qpB;
    qfB1 = *(const short8*)(qpB + 32);
  }

  // mask vector pointers: lane's q-row, element offset 4*lq; +kv0+16f at use
  const float* mvA = mb + (size_t)(qbaseA + lr) * SEQ + 4 * lq;
  const float* mvB = mb + (size_t)(qbaseB + lr) * SEQ + 4 * lq;
  // bias float4 base: component x->r=3, y->r=2, z->r=1, w->r=0
  // value(r) = bt[qrow + 2047 - (kv0+16f+4lq+r)]; base = index at r=3
  const float* btA4 = bt + qbaseA + lr - 4 * lq + 2044;  // - kv0 - 16f at use
  const float* btB4 = btA4 + 16;

  float lAa = 0.f, lAb = 0.f, lBa = 0.f, lBb = 0.f;  // 2 partials per group
  f32x4 ofA[4], ofB[4];
#pragma unroll
  for (int i = 0; i < 4; ++i) {
    ofA[i] = (f32x4){0.f, 0.f, 0.f, 0.f};
    ofB[i] = (f32x4){0.f, 0.f, 0.f, 0.f};
  }

  const int srow = t >> 3;           // staging row 0..31 (+32 for second half)
  const int sseg = t & 7;            // staging 16B segment

  // per-thread staging source bases
  const ushort* kp = kh + (size_t)srow * HD + sseg * 8;   // + kv*HD (+32*HD)
  const ushort* vp = vh + (size_t)srow * SEQ + sseg * 8;  // + kv (+32*SEQ)

  // prologue: tile0 -> regs -> buf0; then tile1 -> regs
  uint4 kr0 = *(const uint4*)(kp);
  uint4 kr1 = *(const uint4*)(kp + 32 * HD);
  uint4 vr0 = *(const uint4*)(vp);
  uint4 vr1 = *(const uint4*)(vp + 32 * SEQ);
  *(uint4*)&Ks[0][srow * 72 + sseg * 8] = kr0;
  *(uint4*)&Ks[0][(32 + srow) * 72 + sseg * 8] = kr1;
  *(uint4*)&Vs[0][srow * 72 + sseg * 8] = vr0;
  *(uint4*)&Vs[0][(32 + srow) * 72 + sseg * 8] = vr1;
  kr0 = *(const uint4*)(kp + 64 * HD);
  kr1 = *(const uint4*)(kp + 96 * HD);
  vr0 = *(const uint4*)(vp + 64);
  vr1 = *(const uint4*)(vp + 64 + 32 * SEQ);

  // group-A mask + bias prefetch for tile 0 (LOAD-ONLY)
  float4 mnA[4], bnA[4];
#pragma unroll
  for (int f = 0; f < 4; ++f) {
    mnA[f] = *(const float4*)(mvA + f * 16);
    bnA[f] = *(const float4*)(btA4 - f * 16);
  }

  for (int it = 0; it < 32; ++it) {
    const int kv0 = it * 64;
    const int cur = it & 1, nxt = cur ^ 1;

    __syncthreads();  // prev writes visible; prev-prev reads of buf[nxt] done

    // write tile it+1 (in regs) into buf[nxt]  (it=31: dead write, never read)
    *(uint4*)&Ks[nxt][srow * 72 + sseg * 8] = kr0;
    *(uint4*)&Ks[nxt][(32 + srow) * 72 + sseg * 8] = kr1;
    *(uint4*)&Vs[nxt][srow * 72 + sseg * 8] = vr0;
    *(uint4*)&Vs[nxt][(32 + srow) * 72 + sseg * 8] = vr1;

    // group-B mask + bias loads for THIS tile (LOAD-ONLY; wait sinks to SM_B)
    float4 mnB[4], bnB[4];
#pragma unroll
    for (int f = 0; f < 4; ++f) {
      mnB[f] = *(const float4*)(mvB + kv0 + f * 16);
      bnB[f] = *(const float4*)(btB4 - kv0 - f * 16);
    }

    // issue tile it+2 staging loads (clamped) — latency spans whole iteration
    const int lkv = (it + 2 < 32) ? (it + 2) * 64 : 0;
    kr0 = *(const uint4*)(kp + (size_t)lkv * HD);
    kr1 = *(const uint4*)(kp + (size_t)(lkv + 32) * HD);
    vr0 = *(const uint4*)(vp + lkv);
    vr1 = *(const uint4*)(vp + lkv + 32 * SEQ);

    // QK (swapped): sf[f][r] = S[qrow = lr][kv = kv0 + 16f + 4lq + r]
    f32x4 sfA[4], sfB[4];
#pragma unroll
    for (int f = 0; f < 4; ++f) {
      const ushort* kfp = &Ks[cur][(f * 16 + lr) * 72 + lq * 8];
      const short8 k0 = *(const short8*)kfp;
      const short8 k1 = *(const short8*)(kfp + 32);
      sfA[f] = (f32x4){0.f, 0.f, 0.f, 0.f};
      sfA[f] = __builtin_amdgcn_mfma_f32_16x16x32_bf16(k0, qfA0, sfA[f], 0, 0, 0);
      sfA[f] = __builtin_amdgcn_mfma_f32_16x16x32_bf16(k1, qfA1, sfA[f], 0, 0, 0);
      sfB[f] = (f32x4){0.f, 0.f, 0.f, 0.f};
      sfB[f] = __builtin_amdgcn_mfma_f32_16x16x32_bf16(k0, qfB0, sfB[f], 0, 0, 0);
      sfB[f] = __builtin_amdgcn_mfma_f32_16x16x32_bf16(k1, qfB1, sfB[f], 0, 0, 0);
    }

    // SM_A: p = exp2(s*scale*log2e + (mask+bias)*log2e); pack 4 -> b64 write
#pragma unroll
    for (int f = 0; f < 4; ++f) {
      unsigned up0, up1;
#pragma unroll
      for (int r = 0; r < 4; ++r) {
        const float mbv = (&mnA[f].x)[r] + (&bnA[f].x)[3 - r];
        const float xs = fmaf(sfA[f][r], 0.18033688f, mbv * L2E);
        const float p = __builtin_amdgcn_exp2f(xs);
        if (f & 1) lAb += p; else lAa += p;
        const unsigned hh = (__builtin_bit_cast(unsigned, p) + 0x8000u) >> 16;
        if (r == 0) up0 = hh;
        else if (r == 1) up0 |= hh << 16;
        else if (r == 2) up1 = hh;
        else up1 |= hh << 16;
      }
      uint2 pk; pk.x = up0; pk.y = up1;
      *(uint2*)&Ps[w][lr * 72 + 16 * f + 4 * lq] = pk;
    }

    // group-A mask + bias prefetch for NEXT tile (LOAD-ONLY), clamped
    const int mkv = (it + 1 < 32) ? (it + 1) * 64 : 0;
#pragma unroll
    for (int f = 0; f < 4; ++f) {
      mnA[f] = *(const float4*)(mvA + mkv + f * 16);
      bnA[f] = *(const float4*)(btA4 - mkv - f * 16);
    }

    // SM_B: rows 16..31
#pragma unroll
    for (int f = 0; f < 4; ++f) {
      unsigned up0, up1;
#pragma unroll
      for (int r = 0; r < 4; ++r) {
        const float mbv = (&mnB[f].x)[r] + (&bnB[f].x)[3 - r];
        const float xs = fmaf(sfB[f][r], 0.18033688f, mbv * L2E);
        const float p = __builtin_amdgcn_exp2f(xs);
        if (f & 1) lBb += p; else lBa += p;
        const unsigned hh = (__builtin_bit_cast(unsigned, p) + 0x8000u) >> 16;
        if (r == 0) up0 = hh;
        else if (r == 1) up0 |= hh << 16;
        else if (r == 2) up1 = hh;
        else up1 |= hh << 16;
      }
      uint2 pk; pk.x = up0; pk.y = up1;
      *(uint2*)&Ps[w][(16 + lr) * 72 + 16 * f + 4 * lq] = pk;
    }

    // PV for BOTH groups — single b128 Ps reads
#pragma unroll
    for (int ks = 0; ks < 2; ++ks) {
      union { uint4 u; short8 s; } puA, puB;
      puA.u = *(const uint4*)&Ps[w][lr * 72 + ks * 32 + lq * 8];
      puB.u = *(const uint4*)&Ps[w][(16 + lr) * 72 + ks * 32 + lq * 8];
#pragma unroll
      for (int hf = 0; hf < 4; ++hf) {
        const short8 vf =
            *(const short8*)&Vs[cur][(hf * 16 + lr) * 72 + ks * 32 + lq * 8];
        ofA[hf] = __builtin_amdgcn_mfma_f32_16x16x32_bf16(puA.s, vf, ofA[hf], 0, 0, 0);
        ofB[hf] = __builtin_amdgcn_mfma_f32_16x16x32_bf16(puB.s, vf, ofB[hf], 0, 0, 0);
      }
    }
  }

  // l: sum across the 4 lq groups (lanes xor 16, 32); lane then holds
  // l[qrow = lr] of its group. Redistribute so (lq,r) gets l[lq*4+r].
  float vA = lAa + lAb;
  vA += __shfl_xor(vA, 16); vA += __shfl_xor(vA, 32);
  float vB = lBa + lBb;
  vB += __shfl_xor(vB, 16); vB += __shfl_xor(vB, 32);

#pragma unroll
  for (int r = 0; r < 4; ++r) {
    const float invA = 1.0f / __shfl(vA, (lane & 48) | (lq * 4 + r));
    const int qrA = qbaseA + lq * 4 + r;
    ushort* opA = Out + ((size_t)(b * SEQ + qrA)) * CDIM + h * HD;
#pragma unroll
    for (int hf = 0; hf < 4; ++hf) opA[hf * 16 + lr] = f32_to_bf16_rn(ofA[hf][r] * invA);
    const float invB = 1.0f / __shfl(vB, (lane & 48) | (lq * 4 + r));
    const int qrB = qbaseB + lq * 4 + r;
    ushort* opB = Out + ((size_t)(b * SEQ + qrB)) * CDIM + h * HD;
#pragma unroll
    for (int hf = 0; hf < 4; ++hf) opB[hf * 16 + lr] = f32_to_bf16_rn(ofB[hf][r] * invB);
  }
}

// ---------------------------------------------------------------------------
extern "C" void kernel_launch(void* const* d_in, const int* in_sizes, int n_in,
                              void* d_out, int out_size, void* d_ws, size_t ws_size,
                              hipStream_t stream) {
  const float* x     = (const float*)d_in[0];
  const float* mask  = (const float*)d_in[1];
  const float* Wqkv  = (const float*)d_in[2];
  const float* Btab  = (const float*)d_in[3];
  const float* Wproj = (const float*)d_in[4];
  const float* bproj = (const float*)d_in[5];
  float* out = (float*)d_out;

  char* ws = (char*)d_ws;
  const size_t SZ_X   = (size_t)NBATCH * SEQ * CDIM;
  const size_t SZ_QKV = (size_t)3 * CDIM * CDIM;
  const size_t SZ_PRJ = (size_t)CDIM * CDIM;
  const size_t SZ_HD  = (size_t)NBATCH * NHEAD * SEQ * HD;

  ushort* xb    = (ushort*)ws; ws += SZ_X * 2;
  ushort* wqkvb = (ushort*)ws; ws += SZ_QKV * 2;
  ushort* wprjb = (ushort*)ws; ws += SZ_PRJ * 2;
  ushort* qb    = (ushort*)ws; ws += SZ_HD * 2;
  ushort* kb    = (ushort*)ws; ws += SZ_HD * 2;
  ushort* vtb   = (ushort*)ws; ws += SZ_HD * 2;
  ushort* aob   = (ushort*)ws; ws += SZ_X * 2;

  {
    int n4 = (int)(SZ_X / 4);
    int g = (n4 + 255) / 256; if (g > 4096) g = 4096;
    cvt_f32_bf16<<<g, 256, 0, stream>>>(x, xb, n4);
  }
  {
    int n4 = (int)(SZ_QKV / 4);
    cvt_f32_bf16<<<(n4 + 255) / 256, 256, 0, stream>>>(Wqkv, wqkvb, n4);
  }
  {
    int n4 = (int)(SZ_PRJ / 4);
    cvt_f32_bf16<<<(n4 + 255) / 256, 256, 0, stream>>>(Wproj, wprjb, n4);
  }

  // QKV: M=8192, N=1536, K=512
  gemm_nt<0><<<dim3(12, 64), 256, 0, stream>>>(xb, wqkvb, qb, kb, vtb, nullptr, nullptr);

  // fused attention (1D swizzled grid, 256-thread blocks, 128 q-rows each)
  attn_fused<<<dim3(512), 256, 0, stream>>>(qb, kb, vtb, mask, Btab, aob);

  // proj: M=8192, N=512, K=512, +bias, f32 out
  gemm_nt<1><<<dim3(4, 64), 256, 0, stream>>>(aob, wprjb, nullptr, nullptr, nullptr, bproj, out);
}